// Round 13
// baseline (116.406 us; speedup 1.0000x reference)
//
#include <hip/hip_runtime.h>

// Problem constants: B=4, S=512, H=256
#define Bn 4
#define Sn 512
#define Hn 256

#define CC   2.8853900817779268f   // 2*log2(e)
#define L2E  1.4426950408889634f

typedef __attribute__((ext_vector_type(4))) float f32x4;
typedef __attribute__((ext_vector_type(8))) short short8;

__device__ __forceinline__ unsigned short bf16rn(float f) {
    unsigned int u = __float_as_uint(f);
    u += 0x7fffu + ((u >> 16) & 1u);
    return (unsigned short)(u >> 16);
}
__device__ __forceinline__ float bf16tof(unsigned short b) {
    return __uint_as_float(((unsigned int)b) << 16);
}

// ---------------------------------------------------------------------------
// prep: merged splitA (h -> h1,h2 bf16 planes; 256 blocks) and splitB
// (Wt/Wp -> transposed bf16 split planes; 32 blocks). 288 blocks x 256 thr.
// ---------------------------------------------------------------------------
__global__ __launch_bounds__(256) void prep_kernel(
    const float* __restrict__ h,  const float* __restrict__ Wt,
    const float* __restrict__ Wp, const float* __restrict__ Wa,
    const float* __restrict__ ba,
    unsigned short* __restrict__ h1, unsigned short* __restrict__ h2,
    unsigned short* __restrict__ wtp,
    float* __restrict__ wa2, float* __restrict__ cst)
{
    __shared__ float tile[64 * 68];
    __shared__ float red4[4];
    const int tid = threadIdx.x;
    const int bid = blockIdx.x;

    if (bid < 256) {
        const int base = (bid * 256 + tid) * 8;
        float4 v0 = *(const float4*)&h[base];
        float4 v1 = *(const float4*)&h[base + 4];
        float f[8] = {v0.x, v0.y, v0.z, v0.w, v1.x, v1.y, v1.z, v1.w};
        unsigned short b1[8], b2[8];
#pragma unroll
        for (int i = 0; i < 8; i++) {
            b1[i] = bf16rn(f[i]);
            b2[i] = bf16rn(f[i] - bf16tof(b1[i]));
        }
        uint4 u1, u2;
        u1.x = (unsigned)b1[0] | ((unsigned)b1[1] << 16);
        u1.y = (unsigned)b1[2] | ((unsigned)b1[3] << 16);
        u1.z = (unsigned)b1[4] | ((unsigned)b1[5] << 16);
        u1.w = (unsigned)b1[6] | ((unsigned)b1[7] << 16);
        u2.x = (unsigned)b2[0] | ((unsigned)b2[1] << 16);
        u2.y = (unsigned)b2[2] | ((unsigned)b2[3] << 16);
        u2.z = (unsigned)b2[4] | ((unsigned)b2[5] << 16);
        u2.w = (unsigned)b2[6] | ((unsigned)b2[7] << 16);
        *(uint4*)&h1[base] = u1;
        *(uint4*)&h2[base] = u2;

        if (bid == 0) {
            float w = Wa[tid];
#pragma unroll
            for (int off = 32; off >= 1; off >>= 1) w += __shfl_xor(w, off, 64);
            if ((tid & 63) == 0) red4[tid >> 6] = w;
            __syncthreads();
            wa2[tid] = -2.0f * Wa[tid];
            if (tid == 0)
                cst[0] = -L2E * ((red4[0] + red4[1] + red4[2] + red4[3]) + ba[0]);
        }
    } else {
        const int sb  = bid - 256;
        const int mat = sb >> 4;
        const int t4  = sb & 15;
        const int k0  = (t4 >> 2) * 64, n0 = (t4 & 3) * 64;
        const float* __restrict__ W = mat ? Wp : Wt;

#pragma unroll
        for (int i = 0; i < 4; i++) {
            const int idx = tid + 256 * i;
            const int kr = idx >> 4, nq = idx & 15;
            *(float4*)&tile[kr * 68 + nq * 4] =
                *(const float4*)&W[(k0 + kr) * Hn + n0 + nq * 4];
        }
        __syncthreads();

        unsigned short* p1 = wtp + mat * 2 * 65536;
        unsigned short* p2 = p1 + 65536;
#pragma unroll
        for (int i = 0; i < 8; i++) {
            const int idx = tid + 256 * i;
            const int n = idx >> 5, kp = idx & 31;
            const float f0 = tile[(2 * kp) * 68 + n];
            const float f1 = tile[(2 * kp + 1) * 68 + n];
            const unsigned short a0 = bf16rn(f0), a1 = bf16rn(f1);
            const unsigned short c0 = bf16rn(f0 - bf16tof(a0));
            const unsigned short c1 = bf16rn(f1 - bf16tof(a1));
            const int dw = ((n0 + n) * 256 + k0) / 2 + kp;
            ((unsigned int*)p1)[dw] = (unsigned)a0 | ((unsigned)a1 << 16);
            ((unsigned int*)p2)[dw] = (unsigned)c0 | ((unsigned)c1 << 16);
        }
    }
}

// ---------------------------------------------------------------------------
// gemm: C[2048][512] = h @ [Wt|Wp] via 16x16x32 bf16 MFMA, split-precision
// (a1w1 + a1w2 + a2w1). Fused exp2 epilogue -> Egt / Egp4. 256 blk x 256 thr.
// ---------------------------------------------------------------------------
__global__ __launch_bounds__(256) void gemm_kernel(
    const unsigned short* __restrict__ h1, const unsigned short* __restrict__ h2,
    const unsigned short* __restrict__ wtp, const float* __restrict__ bh,
    float* __restrict__ Egt, float* __restrict__ Egp4)
{
    __shared__ char lds[20480];

    const int tid = threadIdx.x;
    const int mb = blockIdx.x >> 3;
    const int nb = blockIdx.x & 7;
    const int m0 = mb * 64;
    const bool isT = (nb < 4);
    const int n0l = isT ? nb * 64 : (nb - 4) * 64;
    const unsigned short* pB1 = wtp + (isT ? 0 : 2 * 65536);
    const unsigned short* pB2 = pB1 + 65536;

    const int w    = tid >> 6;
    const int lane = tid & 63;
    const int quad = lane >> 4;
    const int l15  = lane & 15;

    f32x4 acc[4];
#pragma unroll
    for (int i = 0; i < 4; i++) acc[i] = (f32x4){0.f, 0.f, 0.f, 0.f};

    const int ssel = tid >> 7;
    const int spl  = (tid >> 6) & 1;
    const int srow = (tid & 63) >> 2;
    const int sseg = tid & 3;
    const unsigned short* gsrc =
        (ssel == 0) ? (spl ? h2 : h1) : (spl ? pB2 : pB1);
    const int growbase = (ssel == 0) ? m0 : n0l;
    char* ldsdst = lds + (ssel * 2 + spl) * 5120;

    for (int ks = 0; ks < 256; ks += 32) {
        __syncthreads();
#pragma unroll
        for (int i = 0; i < 4; i++) {
            const int row = srow + i * 16;
            uint4 v = *(const uint4*)&gsrc[(growbase + row) * 256 + ks + sseg * 8];
            *(uint4*)(ldsdst + row * 80 + sseg * 16) = v;
        }
        __syncthreads();

        const char* Ab = lds;
        const char* Bb = lds + 10240;
        const short8 b1 = *(const short8*)(Bb + (w * 16 + l15) * 80 + quad * 16);
        const short8 b2 = *(const short8*)(Bb + 5120 + (w * 16 + l15) * 80 + quad * 16);
#pragma unroll
        for (int mt = 0; mt < 4; mt++) {
            const short8 a1 = *(const short8*)(Ab + (mt * 16 + l15) * 80 + quad * 16);
            const short8 a2 = *(const short8*)(Ab + 5120 + (mt * 16 + l15) * 80 + quad * 16);
            acc[mt] = __builtin_amdgcn_mfma_f32_16x16x32_bf16(a1, b1, acc[mt], 0, 0, 0);
            acc[mt] = __builtin_amdgcn_mfma_f32_16x16x32_bf16(a1, b2, acc[mt], 0, 0, 0);
            acc[mt] = __builtin_amdgcn_mfma_f32_16x16x32_bf16(a2, b1, acc[mt], 0, 0, 0);
        }
    }

    __syncthreads();
    float* ct = (float*)lds;
#pragma unroll
    for (int mt = 0; mt < 4; mt++)
#pragma unroll
        for (int r = 0; r < 4; r++)
            ct[(mt * 16 + quad * 4 + r) * 68 + w * 16 + l15] = acc[mt][r];
    __syncthreads();

    const int b  = m0 >> 9;
    const int s0 = m0 & 511;
    if (isT) {
        const int n0g = nb * 64;
#pragma unroll
        for (int i = 0; i < 4; i++) {
            const int item = tid + i * 256;
            const int mr = item >> 4, nq = item & 15;
            const float4 c  = *(const float4*)&ct[mr * 68 + nq * 4];
            const float4 bv = *(const float4*)&bh[n0g + nq * 4];
            float4 o;
            o.x = __builtin_amdgcn_exp2f((c.x + bv.x) * CC);
            o.y = __builtin_amdgcn_exp2f((c.y + bv.y) * CC);
            o.z = __builtin_amdgcn_exp2f((c.z + bv.z) * CC);
            o.w = __builtin_amdgcn_exp2f((c.w + bv.w) * CC);
            *(float4*)&Egt[(m0 + mr) * Hn + n0g + nq * 4] = o;
        }
    } else {
        const int kq0 = (nb - 4) * 16;
#pragma unroll
        for (int i = 0; i < 4; i++) {
            const int item = tid + i * 256;
            const int mr = item & 63, nq = item >> 6;
            const float4 c = *(const float4*)&ct[mr * 68 + nq * 4];
            float4 o;
            o.x = __builtin_amdgcn_exp2f(c.x * CC);
            o.y = __builtin_amdgcn_exp2f(c.y * CC);
            o.z = __builtin_amdgcn_exp2f(c.z * CC);
            o.w = __builtin_amdgcn_exp2f(c.w * CC);
            *(float4*)&Egp4[b * 131072 + (kq0 + nq) * 2048 + (s0 + mr) * 4] = o;
        }
    }
}

// ---------------------------------------------------------------------------
// attn: R10 structure (best measured: 46.3us, VGPR 32, occ 60%) + R13 change:
// SOFTWARE-PIPELINED SCALAR LOADS. The 5 s_load_dwordx4 per kk (w4 + 4 egt
// rows, ~100-200cy scalar-cache latency) were consumed in the issuing
// iteration -- the last unpipelined fetch stream (ep prefetch was neutral in
// R12; LDS-vs-scalar choice neutral in R9/R10 -- both point at broadcast
// operand LATENCY as the stall). Rotate 20 SGPR-resident floats one kk ahead;
// unroll 2 folds the rotation into register renaming. Occupancy-free.
// ---------------------------------------------------------------------------
__global__ __launch_bounds__(1024) void attn_kernel(
    const float* __restrict__ hsrc, const float* __restrict__ Egt,
    const float* __restrict__ Egp4, const float* __restrict__ wa2,
    const float* __restrict__ cst,
    float* __restrict__ out, float* __restrict__ out_attn)
{
    // [0,8K) attn_l[4][512] ; [8K,16K) accl[4][512] ; [16K,16.25K) red ;
    // part[8][4][64]f4 32KB aliases [8K,40K) (phase 2 only; accl/red dead)
    __shared__ char smem[40960];
    float*  attn_l = (float*)smem;
    float*  accl   = (float*)(smem + 8192);
    float*  red    = (float*)(smem + 16384);
    float4* part   = (float4*)(smem + 8192);

    const int tid = threadIdx.x;       // 0..1023
    const int tp  = tid & 511;
    const int kh  = tid >> 9;          // 0 or 1: k-half (wave-uniform)
    const int b   = blockIdx.x & 3;
    const int t0  = (blockIdx.x >> 2) << 2;

    // wave-uniform scalar base for this half's k4 range
    const int kbu = __builtin_amdgcn_readfirstlane(kh << 5);

    const float* __restrict__ egt = Egt + (b * Sn + t0) * Hn;   // block-uniform
    const float4* __restrict__ ep = (const float4*)(Egp4 + b * (Hn * Sn));

    float acc[4] = {0.f, 0.f, 0.f, 0.f};

    // preload kk=0 scalar operands (SGPR-resident; wave-uniform addresses)
    float4 w4c  = *(const float4*)&wa2[kbu * 4];
    float4 eg0c = *(const float4*)&egt[0 * Hn + kbu * 4];
    float4 eg1c = *(const float4*)&egt[1 * Hn + kbu * 4];
    float4 eg2c = *(const float4*)&egt[2 * Hn + kbu * 4];
    float4 eg3c = *(const float4*)&egt[3 * Hn + kbu * 4];

#pragma unroll 2
    for (int kk = 0; kk < 32; kk++) {
        // prefetch next iteration's scalars (wrap avoids OOB; tail redundant)
        const int k4n = kbu + ((kk + 1) & 31);
        const float4 w4n  = *(const float4*)&wa2[k4n * 4];
        const float4 eg0n = *(const float4*)&egt[0 * Hn + k4n * 4];
        const float4 eg1n = *(const float4*)&egt[1 * Hn + k4n * 4];
        const float4 eg2n = *(const float4*)&egt[2 * Hn + k4n * 4];
        const float4 eg3n = *(const float4*)&egt[3 * Hn + k4n * 4];

        const float4 cur = ep[(kbu + kk) * Sn + tp];   // coalesced vector load

        const float4 egs[4] = {eg0c, eg1c, eg2c, eg3c};
#pragma unroll
        for (int r = 0; r < 4; r++) {
            const float4 eg = egs[r];
            const float d1 = fmaf(cur.x, eg.x, 1.0f);
            const float d2 = fmaf(cur.y, eg.y, 1.0f);
            const float d3 = fmaf(cur.z, eg.z, 1.0f);
            const float d4 = fmaf(cur.w, eg.w, 1.0f);
            const float p12 = d1 * d2, p34 = d3 * d4;
            const float n12 = fmaf(w4c.x, d2, w4c.y * d1);
            const float n34 = fmaf(w4c.z, d4, w4c.w * d3);
            const float num = fmaf(n12, p34, n34 * p12);
            acc[r] = fmaf(num, __builtin_amdgcn_rcpf(p12 * p34), acc[r]);
        }

        w4c = w4n; eg0c = eg0n; eg1c = eg1n; eg2c = eg2n; eg3c = eg3n;
    }

    if (kh == 1) {
#pragma unroll
        for (int r = 0; r < 4; r++) accl[r * 512 + tp] = acc[r];
    }
    __syncthreads();

    float ex[4];
    const float k0 = cst[0];
    if (kh == 0) {
#pragma unroll
        for (int r = 0; r < 4; r++) {
            const float a   = acc[r] + accl[r * 512 + tp];
            const float e1  = __builtin_amdgcn_exp2f(fmaf(-L2E, a, k0));
            const float sig = __builtin_amdgcn_rcpf(1.0f + e1);
            ex[r] = __builtin_amdgcn_exp2f(L2E * sig);   // sig in (0,1)
        }
        const int lane = tid & 63, wid = tid >> 6;       // wid 0..7
#pragma unroll
        for (int r = 0; r < 4; r++) {
            float v = ex[r];
#pragma unroll
            for (int off = 32; off >= 1; off >>= 1) v += __shfl_xor(v, off, 64);
            if (lane == 0) red[r * 8 + wid] = v;
        }
    }
    __syncthreads();

    if (kh == 0) {
#pragma unroll
        for (int r = 0; r < 4; r++) {
            float tot = 0.f;
#pragma unroll
            for (int i = 0; i < 8; i++) tot += red[r * 8 + i];
            const float a = ex[r] * __builtin_amdgcn_rcpf(tot);
            attn_l[r * Sn + tp] = a;
            out_attn[(b * Sn + t0 + r) * Sn + tp] = a;
        }
    }
    __syncthreads();

    // ---- phase 2: out rows = attn @ h. 16 q-groups of 32 t' each ----
    const int c4 = tid & 63;
    const int q  = tid >> 6;                 // 0..15, wave-uniform

    const float* __restrict__ hb = hsrc + (b * Sn + q * 32) * Hn + c4 * 4;

    float4 a4[4];
#pragma unroll
    for (int r = 0; r < 4; r++) a4[r] = (float4){0.f, 0.f, 0.f, 0.f};

#pragma unroll 2
    for (int j4 = 0; j4 < 8; j4++) {
        float4 wv[4];
#pragma unroll
        for (int r = 0; r < 4; r++)
            wv[r] = *(const float4*)&attn_l[r * Sn + q * 32 + j4 * 4];  // bcast
#pragma unroll
        for (int i = 0; i < 4; i++) {
            const float4 hv = *(const float4*)&hb[(j4 * 4 + i) * Hn];
#pragma unroll
            for (int r = 0; r < 4; r++) {
                const float wr = ((const float*)&wv[r])[i];
                a4[r].x = fmaf(wr, hv.x, a4[r].x);
                a4[r].y = fmaf(wr, hv.y, a4[r].y);
                a4[r].z = fmaf(wr, hv.z, a4[r].z);
                a4[r].w = fmaf(wr, hv.w, a4[r].w);
            }
        }
    }
    __syncthreads();   // accl/red reads all done; part may now alias

    if (q < 8) {
#pragma unroll
        for (int r = 0; r < 4; r++) part[(q * 4 + r) * 64 + c4] = a4[r];
    }
    __syncthreads();
    if (q >= 8) {
#pragma unroll
        for (int r = 0; r < 4; r++) {
            float4 p = part[((q - 8) * 4 + r) * 64 + c4];
            p.x += a4[r].x; p.y += a4[r].y; p.z += a4[r].z; p.w += a4[r].w;
            part[((q - 8) * 4 + r) * 64 + c4] = p;
        }
    }
    __syncthreads();

    // final: 1024 threads = 256 cols x 4 rows; sum the 8 q-partials
    {
        const int col = tid & 255;
        const int r   = tid >> 8;
        const float* pf = (const float*)part;
        float s = 0.f;
#pragma unroll
        for (int qq = 0; qq < 8; qq++)
            s += pf[((qq * 4 + r) * 64 + (col >> 2)) * 4 + (col & 3)];
        out[(b * Sn + t0 + r) * Hn + col] = s;
    }
}

extern "C" void kernel_launch(void* const* d_in, const int* in_sizes, int n_in,
                              void* d_out, int out_size, void* d_ws, size_t ws_size,
                              hipStream_t stream) {
    const float* h   = (const float*)d_in[0];
    const float* Wt  = (const float*)d_in[1];
    const float* Wtp = (const float*)d_in[2];
    const float* bh  = (const float*)d_in[3];
    const float* Wa  = (const float*)d_in[4];
    const float* ba  = (const float*)d_in[5];

    float* out      = (float*)d_out;                 // (B,S,H) = 524288
    float* out_attn = out + Bn * Sn * Hn;            // (B,S,S) = 1048576

    float* ws   = (float*)d_ws;
    float* Egt  = ws;                                 // 524288 f
    float* Egp4 = ws + 524288;                        // 524288 f
    float* wa2  = ws + 1048576;                       // 256 f
    float* cst  = ws + 1048832;                       // 1 f
    unsigned short* h1  = (unsigned short*)(ws + 1048840);   // 524288 us
    unsigned short* h2  = h1 + 2048 * 256;                   // 524288 us
    unsigned short* wtp = h2 + 2048 * 256;                   // 4 x 65536 us

    prep_kernel<<<dim3(288), dim3(256), 0, stream>>>(
        h, Wt, Wtp, Wa, ba, h1, h2, wtp, wa2, cst);
    gemm_kernel<<<dim3(256), dim3(256), 0, stream>>>(h1, h2, wtp, bh, Egt, Egp4);
    attn_kernel<<<dim3(Bn * (Sn / 4)), dim3(1024), 0, stream>>>(
        h, Egt, Egp4, wa2, cst, out, out_attn);
}

// Round 14
// 114.306 us; speedup vs baseline: 1.0184x; 1.0184x over previous
//
#include <hip/hip_runtime.h>

// Problem constants: B=4, S=512, H=256
#define Bn 4
#define Sn 512
#define Hn 256

#define CC   2.8853900817779268f   // 2*log2(e)
#define L2E  1.4426950408889634f

typedef __attribute__((ext_vector_type(4))) float f32x4;
typedef __attribute__((ext_vector_type(8))) short short8;

__device__ __forceinline__ unsigned short bf16rn(float f) {
    unsigned int u = __float_as_uint(f);
    u += 0x7fffu + ((u >> 16) & 1u);
    return (unsigned short)(u >> 16);
}
__device__ __forceinline__ float bf16tof(unsigned short b) {
    return __uint_as_float(((unsigned int)b) << 16);
}

// ---------------------------------------------------------------------------
// gemm (prep folded in, R14): C[2048][512] = h @ [Wt|Wp] via 16x16x32 bf16
// MFMA, split-precision (a1w1 + a1w2 + a2w1). Each block builds its OWN
// bf16 split planes in LDS (A from its 64 h-rows, B via tile-transpose from
// W) -- eliminates the prep kernel, its dispatch gap, and the 2.5MB global
// round-trip of h1/h2/wtp. Planes: [64][264] shorts (264 = 33 KB/plane;
// stride chosen for balanced b128 bank-quad distribution, same as old 80B).
// LDS ~149 KB, grid 256 = 1 block/CU (gemm was 1/CU already).
// Fused exp2 epilogue -> Egt (+bias) / Egp4. wa2/cst computed by block 0.
// ---------------------------------------------------------------------------
__global__ __launch_bounds__(256) void gemm_kernel(
    const float* __restrict__ h,  const float* __restrict__ Wt,
    const float* __restrict__ Wp, const float* __restrict__ Wa,
    const float* __restrict__ ba, const float* __restrict__ bh,
    float* __restrict__ Egt, float* __restrict__ Egp4,
    float* __restrict__ wa2, float* __restrict__ cst)
{
    // A1@0 A2@33792 B1@67584 B2@101376 (each 64*264*2 = 33792 B)
    // tile/ct @135168 (64*68*4 = 17408 B), red4 @152576
    __shared__ char lds[152640];
    unsigned short* A1 = (unsigned short*)lds;
    unsigned short* A2 = (unsigned short*)(lds + 33792);
    unsigned short* B1 = (unsigned short*)(lds + 67584);
    unsigned short* B2 = (unsigned short*)(lds + 101376);
    float* tile = (float*)(lds + 135168);   // 64 x 68 f32; reused as ct
    float* red4 = (float*)(lds + 152576);

    const int tid = threadIdx.x;
    const int mb  = blockIdx.x >> 3;
    const int nb  = blockIdx.x & 7;
    const int m0  = mb * 64;
    const bool isT = (nb < 4);
    const int n0  = (isT ? nb : nb - 4) * 64;
    const float* __restrict__ W = isT ? Wt : Wp;

    // ---- wa2 / cst (block 0 only; block-uniform branch, own barriers) ----
    if (blockIdx.x == 0) {
        float wv = Wa[tid];
#pragma unroll
        for (int off = 32; off >= 1; off >>= 1) wv += __shfl_xor(wv, off, 64);
        if ((tid & 63) == 0) red4[tid >> 6] = wv;
        __syncthreads();
        wa2[tid] = -2.0f * Wa[tid];
        if (tid == 0)
            cst[0] = -L2E * ((red4[0] + red4[1] + red4[2] + red4[3]) + ba[0]);
    }

    // ---- A-fill: split h rows m0..m0+63 into A1/A2 bf16 planes ----
    {
        const int row = tid >> 2;
        const int seg = (tid & 3) * 64;
        const float* __restrict__ src = h + (m0 + row) * Hn + seg;
        unsigned int* d1 = (unsigned int*)A1 + (row * 264 + seg) / 2;
        unsigned int* d2 = (unsigned int*)A2 + (row * 264 + seg) / 2;
#pragma unroll
        for (int i = 0; i < 16; i++) {
            const float4 v = ((const float4*)src)[i];
            const float f[4] = {v.x, v.y, v.z, v.w};
            unsigned short b1[4], b2[4];
#pragma unroll
            for (int j = 0; j < 4; j++) {
                b1[j] = bf16rn(f[j]);
                b2[j] = bf16rn(f[j] - bf16tof(b1[j]));
            }
            d1[2 * i]     = (unsigned)b1[0] | ((unsigned)b1[1] << 16);
            d1[2 * i + 1] = (unsigned)b1[2] | ((unsigned)b1[3] << 16);
            d2[2 * i]     = (unsigned)b2[0] | ((unsigned)b2[1] << 16);
            d2[2 * i + 1] = (unsigned)b2[2] | ((unsigned)b2[3] << 16);
        }
    }

    // ---- B-fill: 4 k-tiles, coalesced read -> tile -> transposed split ----
    for (int kt = 0; kt < 4; kt++) {
        const int k0 = kt * 64;
        __syncthreads();   // protect tile from previous iteration's readers
#pragma unroll
        for (int i = 0; i < 4; i++) {
            const int idx = tid + 256 * i;
            const int kr = idx >> 4, nq = idx & 15;
            *(float4*)&tile[kr * 68 + nq * 4] =
                *(const float4*)&W[(k0 + kr) * Hn + n0 + nq * 4];
        }
        __syncthreads();
#pragma unroll
        for (int i = 0; i < 8; i++) {
            const int idx = tid + 256 * i;
            const int n = idx >> 5, kp = idx & 31;
            const float f0 = tile[(2 * kp) * 68 + n];
            const float f1 = tile[(2 * kp + 1) * 68 + n];
            const unsigned short a0 = bf16rn(f0), a1 = bf16rn(f1);
            const unsigned short c0 = bf16rn(f0 - bf16tof(a0));
            const unsigned short c1 = bf16rn(f1 - bf16tof(a1));
            ((unsigned int*)B1)[n * 132 + k0 / 2 + kp] =
                (unsigned)a0 | ((unsigned)a1 << 16);
            ((unsigned int*)B2)[n * 132 + k0 / 2 + kp] =
                (unsigned)c0 | ((unsigned)c1 << 16);
        }
    }
    __syncthreads();   // A and B planes complete

    // ---- MFMA main loop (sync-free: planes are read-only now) ----
    const int w    = tid >> 6;
    const int lane = tid & 63;
    const int quad = lane >> 4;
    const int l15  = lane & 15;

    f32x4 acc[4];
#pragma unroll
    for (int i = 0; i < 4; i++) acc[i] = (f32x4){0.f, 0.f, 0.f, 0.f};

#pragma unroll 2
    for (int ks = 0; ks < 256; ks += 32) {
        const int bof = (w * 16 + l15) * 264 + ks + quad * 8;
        const short8 b1 = *(const short8*)(B1 + bof);
        const short8 b2 = *(const short8*)(B2 + bof);
#pragma unroll
        for (int mt = 0; mt < 4; mt++) {
            const int aof = (mt * 16 + l15) * 264 + ks + quad * 8;
            const short8 a1 = *(const short8*)(A1 + aof);
            const short8 a2 = *(const short8*)(A2 + aof);
            acc[mt] = __builtin_amdgcn_mfma_f32_16x16x32_bf16(a1, b1, acc[mt], 0, 0, 0);
            acc[mt] = __builtin_amdgcn_mfma_f32_16x16x32_bf16(a1, b2, acc[mt], 0, 0, 0);
            acc[mt] = __builtin_amdgcn_mfma_f32_16x16x32_bf16(a2, b1, acc[mt], 0, 0, 0);
        }
    }

    // ---- epilogue: frag -> ct (aliases tile) -> exp2 -> global ----
    __syncthreads();
    float* ct = tile;
#pragma unroll
    for (int mt = 0; mt < 4; mt++)
#pragma unroll
        for (int r = 0; r < 4; r++)
            ct[(mt * 16 + quad * 4 + r) * 68 + w * 16 + l15] = acc[mt][r];
    __syncthreads();

    const int b  = m0 >> 9;
    const int s0 = m0 & 511;
    if (isT) {
        const int n0g = nb * 64;
#pragma unroll
        for (int i = 0; i < 4; i++) {
            const int item = tid + i * 256;
            const int mr = item >> 4, nq = item & 15;
            const float4 c  = *(const float4*)&ct[mr * 68 + nq * 4];
            const float4 bv = *(const float4*)&bh[n0g + nq * 4];
            float4 o;
            o.x = __builtin_amdgcn_exp2f((c.x + bv.x) * CC);
            o.y = __builtin_amdgcn_exp2f((c.y + bv.y) * CC);
            o.z = __builtin_amdgcn_exp2f((c.z + bv.z) * CC);
            o.w = __builtin_amdgcn_exp2f((c.w + bv.w) * CC);
            *(float4*)&Egt[(m0 + mr) * Hn + n0g + nq * 4] = o;
        }
    } else {
        const int kq0 = (nb - 4) * 16;
#pragma unroll
        for (int i = 0; i < 4; i++) {
            const int item = tid + i * 256;
            const int mr = item & 63, nq = item >> 6;
            const float4 c = *(const float4*)&ct[mr * 68 + nq * 4];
            float4 o;
            o.x = __builtin_amdgcn_exp2f(c.x * CC);
            o.y = __builtin_amdgcn_exp2f(c.y * CC);
            o.z = __builtin_amdgcn_exp2f(c.z * CC);
            o.w = __builtin_amdgcn_exp2f(c.w * CC);
            *(float4*)&Egp4[b * 131072 + (kq0 + nq) * 2048 + (s0 + mr) * 4] = o;
        }
    }
}

// ---------------------------------------------------------------------------
// attn: FROZEN R13 form (best measured 46.0us; every pipelining variant on
// this structure was neutral or regressed -- R11 VGPR bloat, R12 ep prefetch,
// R13 scalar prefetch all within noise of R10). 1024 thr = (tp:512)x(kh:2),
// 4 t-rows, grid 512 -> 32 waves/CU; egt/wa2 via s_load; 4-way-rcp tanh.
// ---------------------------------------------------------------------------
__global__ __launch_bounds__(1024) void attn_kernel(
    const float* __restrict__ hsrc, const float* __restrict__ Egt,
    const float* __restrict__ Egp4, const float* __restrict__ wa2,
    const float* __restrict__ cst,
    float* __restrict__ out, float* __restrict__ out_attn)
{
    // [0,8K) attn_l[4][512] ; [8K,16K) accl[4][512] ; [16K,16.25K) red ;
    // part[8][4][64]f4 32KB aliases [8K,40K) (phase 2 only; accl/red dead)
    __shared__ char smem[40960];
    float*  attn_l = (float*)smem;
    float*  accl   = (float*)(smem + 8192);
    float*  red    = (float*)(smem + 16384);
    float4* part   = (float4*)(smem + 8192);

    const int tid = threadIdx.x;       // 0..1023
    const int tp  = tid & 511;
    const int kh  = tid >> 9;          // 0 or 1: k-half (wave-uniform)
    const int b   = blockIdx.x & 3;
    const int t0  = (blockIdx.x >> 2) << 2;

    const int kbu = __builtin_amdgcn_readfirstlane(kh << 5);

    const float* __restrict__ egt = Egt + (b * Sn + t0) * Hn;   // block-uniform
    const float4* __restrict__ ep = (const float4*)(Egp4 + b * (Hn * Sn));

    float acc[4] = {0.f, 0.f, 0.f, 0.f};

    float4 w4c  = *(const float4*)&wa2[kbu * 4];
    float4 eg0c = *(const float4*)&egt[0 * Hn + kbu * 4];
    float4 eg1c = *(const float4*)&egt[1 * Hn + kbu * 4];
    float4 eg2c = *(const float4*)&egt[2 * Hn + kbu * 4];
    float4 eg3c = *(const float4*)&egt[3 * Hn + kbu * 4];

#pragma unroll 2
    for (int kk = 0; kk < 32; kk++) {
        const int k4n = kbu + ((kk + 1) & 31);
        const float4 w4n  = *(const float4*)&wa2[k4n * 4];
        const float4 eg0n = *(const float4*)&egt[0 * Hn + k4n * 4];
        const float4 eg1n = *(const float4*)&egt[1 * Hn + k4n * 4];
        const float4 eg2n = *(const float4*)&egt[2 * Hn + k4n * 4];
        const float4 eg3n = *(const float4*)&egt[3 * Hn + k4n * 4];

        const float4 cur = ep[(kbu + kk) * Sn + tp];   // coalesced vector load

        const float4 egs[4] = {eg0c, eg1c, eg2c, eg3c};
#pragma unroll
        for (int r = 0; r < 4; r++) {
            const float4 eg = egs[r];
            const float d1 = fmaf(cur.x, eg.x, 1.0f);
            const float d2 = fmaf(cur.y, eg.y, 1.0f);
            const float d3 = fmaf(cur.z, eg.z, 1.0f);
            const float d4 = fmaf(cur.w, eg.w, 1.0f);
            const float p12 = d1 * d2, p34 = d3 * d4;
            const float n12 = fmaf(w4c.x, d2, w4c.y * d1);
            const float n34 = fmaf(w4c.z, d4, w4c.w * d3);
            const float num = fmaf(n12, p34, n34 * p12);
            acc[r] = fmaf(num, __builtin_amdgcn_rcpf(p12 * p34), acc[r]);
        }

        w4c = w4n; eg0c = eg0n; eg1c = eg1n; eg2c = eg2n; eg3c = eg3n;
    }

    if (kh == 1) {
#pragma unroll
        for (int r = 0; r < 4; r++) accl[r * 512 + tp] = acc[r];
    }
    __syncthreads();

    float ex[4];
    const float k0 = cst[0];
    if (kh == 0) {
#pragma unroll
        for (int r = 0; r < 4; r++) {
            const float a   = acc[r] + accl[r * 512 + tp];
            const float e1  = __builtin_amdgcn_exp2f(fmaf(-L2E, a, k0));
            const float sig = __builtin_amdgcn_rcpf(1.0f + e1);
            ex[r] = __builtin_amdgcn_exp2f(L2E * sig);   // sig in (0,1)
        }
        const int lane = tid & 63, wid = tid >> 6;       // wid 0..7
#pragma unroll
        for (int r = 0; r < 4; r++) {
            float v = ex[r];
#pragma unroll
            for (int off = 32; off >= 1; off >>= 1) v += __shfl_xor(v, off, 64);
            if (lane == 0) red[r * 8 + wid] = v;
        }
    }
    __syncthreads();

    if (kh == 0) {
#pragma unroll
        for (int r = 0; r < 4; r++) {
            float tot = 0.f;
#pragma unroll
            for (int i = 0; i < 8; i++) tot += red[r * 8 + i];
            const float a = ex[r] * __builtin_amdgcn_rcpf(tot);
            attn_l[r * Sn + tp] = a;
            out_attn[(b * Sn + t0 + r) * Sn + tp] = a;
        }
    }
    __syncthreads();

    // ---- phase 2: out rows = attn @ h. 16 q-groups of 32 t' each ----
    const int c4 = tid & 63;
    const int q  = tid >> 6;                 // 0..15, wave-uniform

    const float* __restrict__ hb = hsrc + (b * Sn + q * 32) * Hn + c4 * 4;

    float4 a4[4];
#pragma unroll
    for (int r = 0; r < 4; r++) a4[r] = (float4){0.f, 0.f, 0.f, 0.f};

#pragma unroll 2
    for (int j4 = 0; j4 < 8; j4++) {
        float4 wv[4];
#pragma unroll
        for (int r = 0; r < 4; r++)
            wv[r] = *(const float4*)&attn_l[r * Sn + q * 32 + j4 * 4];  // bcast
#pragma unroll
        for (int i = 0; i < 4; i++) {
            const float4 hv = *(const float4*)&hb[(j4 * 4 + i) * Hn];
#pragma unroll
            for (int r = 0; r < 4; r++) {
                const float wr = ((const float*)&wv[r])[i];
                a4[r].x = fmaf(wr, hv.x, a4[r].x);
                a4[r].y = fmaf(wr, hv.y, a4[r].y);
                a4[r].z = fmaf(wr, hv.z, a4[r].z);
                a4[r].w = fmaf(wr, hv.w, a4[r].w);
            }
        }
    }
    __syncthreads();   // accl/red reads all done; part may now alias

    if (q < 8) {
#pragma unroll
        for (int r = 0; r < 4; r++) part[(q * 4 + r) * 64 + c4] = a4[r];
    }
    __syncthreads();
    if (q >= 8) {
#pragma unroll
        for (int r = 0; r < 4; r++) {
            float4 p = part[((q - 8) * 4 + r) * 64 + c4];
            p.x += a4[r].x; p.y += a4[r].y; p.z += a4[r].z; p.w += a4[r].w;
            part[((q - 8) * 4 + r) * 64 + c4] = p;
        }
    }
    __syncthreads();

    // final: 1024 threads = 256 cols x 4 rows; sum the 8 q-partials
    {
        const int col = tid & 255;
        const int r   = tid >> 8;
        const float* pf = (const float*)part;
        float s = 0.f;
#pragma unroll
        for (int qq = 0; qq < 8; qq++)
            s += pf[((qq * 4 + r) * 64 + (col >> 2)) * 4 + (col & 3)];
        out[(b * Sn + t0 + r) * Hn + col] = s;
    }
}

extern "C" void kernel_launch(void* const* d_in, const int* in_sizes, int n_in,
                              void* d_out, int out_size, void* d_ws, size_t ws_size,
                              hipStream_t stream) {
    const float* h   = (const float*)d_in[0];
    const float* Wt  = (const float*)d_in[1];
    const float* Wtp = (const float*)d_in[2];
    const float* bh  = (const float*)d_in[3];
    const float* Wa  = (const float*)d_in[4];
    const float* ba  = (const float*)d_in[5];

    float* out      = (float*)d_out;                 // (B,S,H) = 524288
    float* out_attn = out + Bn * Sn * Hn;            // (B,S,S) = 1048576

    float* ws   = (float*)d_ws;
    float* Egt  = ws;                                 // 524288 f
    float* Egp4 = ws + 524288;                        // 524288 f
    float* wa2  = ws + 1048576;                       // 256 f
    float* cst  = ws + 1048832;                       // 1 f

    gemm_kernel<<<dim3(256), dim3(256), 0, stream>>>(
        h, Wt, Wtp, Wa, ba, bh, Egt, Egp4, wa2, cst);
    attn_kernel<<<dim3(Bn * (Sn / 4)), dim3(1024), 0, stream>>>(
        h, Egt, Egp4, wa2, cst, out, out_attn);
}

// Round 15
// 112.628 us; speedup vs baseline: 1.0335x; 1.0149x over previous
//
#include <hip/hip_runtime.h>

// Problem constants: B=4, S=512, H=256
#define Bn 4
#define Sn 512
#define Hn 256

#define CC   2.8853900817779268f   // 2*log2(e)
#define L2E  1.4426950408889634f

typedef __attribute__((ext_vector_type(4))) float f32x4;
typedef __attribute__((ext_vector_type(8))) short short8;

__device__ __forceinline__ unsigned short bf16rn(float f) {
    unsigned int u = __float_as_uint(f);
    u += 0x7fffu + ((u >> 16) & 1u);
    return (unsigned short)(u >> 16);
}
__device__ __forceinline__ float bf16tof(unsigned short b) {
    return __uint_as_float(((unsigned int)b) << 16);
}

// ---------------------------------------------------------------------------
// gemm (R15: 512 threads = 8 waves/CU; R14 ran 256 thr = 4 waves and the
// bf16-conversion fill phase was latency-starved). Same 256 blocks, same
// ~149 KB LDS split planes, half the fill work per thread, MFMA split as
// (mh = m-half, w2 = n-quadrant) x 2 m-tiles per wave.
// ---------------------------------------------------------------------------
__global__ __launch_bounds__(512) void gemm_kernel(
    const float* __restrict__ h,  const float* __restrict__ Wt,
    const float* __restrict__ Wp, const float* __restrict__ Wa,
    const float* __restrict__ ba, const float* __restrict__ bh,
    float* __restrict__ Egt, float* __restrict__ Egp4,
    float* __restrict__ wa2, float* __restrict__ cst)
{
    // A1@0 A2@33792 B1@67584 B2@101376 (each 64*264*2 = 33792 B)
    // tile/ct @135168 (64*68*4 = 17408 B), red4 @152576
    __shared__ char lds[152640];
    unsigned short* A1 = (unsigned short*)lds;
    unsigned short* A2 = (unsigned short*)(lds + 33792);
    unsigned short* B1 = (unsigned short*)(lds + 67584);
    unsigned short* B2 = (unsigned short*)(lds + 101376);
    float* tile = (float*)(lds + 135168);   // 64 x 68 f32; reused as ct
    float* red4 = (float*)(lds + 152576);

    const int tid = threadIdx.x;            // 0..511
    const int mb  = blockIdx.x >> 3;
    const int nb  = blockIdx.x & 7;
    const int m0  = mb * 64;
    const bool isT = (nb < 4);
    const int n0  = (isT ? nb : nb - 4) * 64;
    const float* __restrict__ W = isT ? Wt : Wp;

    // ---- wa2 / cst (block 0 only; block-uniform branch) ----
    if (blockIdx.x == 0) {
        if (tid < 256) {
            float wv = Wa[tid];
#pragma unroll
            for (int off = 32; off >= 1; off >>= 1) wv += __shfl_xor(wv, off, 64);
            if ((tid & 63) == 0) red4[tid >> 6] = wv;
        }
        __syncthreads();
        if (tid < 256) wa2[tid] = -2.0f * Wa[tid];
        if (tid == 0)
            cst[0] = -L2E * ((red4[0] + red4[1] + red4[2] + red4[3]) + ba[0]);
    }

    // ---- A-fill: split h rows m0..m0+63 into A1/A2 (8 float4 / thread) ----
    {
        const int row = tid >> 3;           // 0..63
        const int seg = (tid & 7) * 32;     // 0..224
        const float* __restrict__ src = h + (m0 + row) * Hn + seg;
        unsigned int* d1 = (unsigned int*)A1 + (row * 264 + seg) / 2;
        unsigned int* d2 = (unsigned int*)A2 + (row * 264 + seg) / 2;
#pragma unroll
        for (int i = 0; i < 8; i++) {
            const float4 v = ((const float4*)src)[i];
            const float f[4] = {v.x, v.y, v.z, v.w};
            unsigned short b1[4], b2[4];
#pragma unroll
            for (int j = 0; j < 4; j++) {
                b1[j] = bf16rn(f[j]);
                b2[j] = bf16rn(f[j] - bf16tof(b1[j]));
            }
            d1[2 * i]     = (unsigned)b1[0] | ((unsigned)b1[1] << 16);
            d1[2 * i + 1] = (unsigned)b1[2] | ((unsigned)b1[3] << 16);
            d2[2 * i]     = (unsigned)b2[0] | ((unsigned)b2[1] << 16);
            d2[2 * i + 1] = (unsigned)b2[2] | ((unsigned)b2[3] << 16);
        }
    }

    // ---- B-fill: 4 k-tiles, coalesced read -> tile -> transposed split ----
    for (int kt = 0; kt < 4; kt++) {
        const int k0 = kt * 64;
        __syncthreads();   // protect tile from previous iteration's readers
#pragma unroll
        for (int i = 0; i < 2; i++) {
            const int idx = tid + 512 * i;           // 1024 float4
            const int kr = idx >> 4, nq = idx & 15;
            *(float4*)&tile[kr * 68 + nq * 4] =
                *(const float4*)&W[(k0 + kr) * Hn + n0 + nq * 4];
        }
        __syncthreads();
#pragma unroll
        for (int i = 0; i < 4; i++) {
            const int idx = tid + 512 * i;           // 2048 uint pairs
            const int n = idx >> 5, kp = idx & 31;
            const float f0 = tile[(2 * kp) * 68 + n];
            const float f1 = tile[(2 * kp + 1) * 68 + n];
            const unsigned short a0 = bf16rn(f0), a1 = bf16rn(f1);
            const unsigned short c0 = bf16rn(f0 - bf16tof(a0));
            const unsigned short c1 = bf16rn(f1 - bf16tof(a1));
            ((unsigned int*)B1)[n * 132 + k0 / 2 + kp] =
                (unsigned)a0 | ((unsigned)a1 << 16);
            ((unsigned int*)B2)[n * 132 + k0 / 2 + kp] =
                (unsigned)c0 | ((unsigned)c1 << 16);
        }
    }
    __syncthreads();   // A and B planes complete

    // ---- MFMA main loop (sync-free). 8 waves: w2 = n-quad, mh = m-half ----
    const int w    = tid >> 6;              // 0..7
    const int w2   = w & 3;                 // n-quadrant
    const int mh   = w >> 2;                // m-half
    const int lane = tid & 63;
    const int quad = lane >> 4;
    const int l15  = lane & 15;

    f32x4 acc[2];
#pragma unroll
    for (int i = 0; i < 2; i++) acc[i] = (f32x4){0.f, 0.f, 0.f, 0.f};

#pragma unroll 2
    for (int ks = 0; ks < 256; ks += 32) {
        const int bof = (w2 * 16 + l15) * 264 + ks + quad * 8;
        const short8 b1 = *(const short8*)(B1 + bof);
        const short8 b2 = *(const short8*)(B2 + bof);
#pragma unroll
        for (int mi = 0; mi < 2; mi++) {
            const int mt = mh * 2 + mi;
            const int aof = (mt * 16 + l15) * 264 + ks + quad * 8;
            const short8 a1 = *(const short8*)(A1 + aof);
            const short8 a2 = *(const short8*)(A2 + aof);
            acc[mi] = __builtin_amdgcn_mfma_f32_16x16x32_bf16(a1, b1, acc[mi], 0, 0, 0);
            acc[mi] = __builtin_amdgcn_mfma_f32_16x16x32_bf16(a1, b2, acc[mi], 0, 0, 0);
            acc[mi] = __builtin_amdgcn_mfma_f32_16x16x32_bf16(a2, b1, acc[mi], 0, 0, 0);
        }
    }

    // ---- epilogue: frag -> ct (aliases tile) -> exp2 -> global ----
    __syncthreads();
    float* ct = tile;
#pragma unroll
    for (int mi = 0; mi < 2; mi++) {
        const int mt = mh * 2 + mi;
#pragma unroll
        for (int r = 0; r < 4; r++)
            ct[(mt * 16 + quad * 4 + r) * 68 + w2 * 16 + l15] = acc[mi][r];
    }
    __syncthreads();

    const int b  = m0 >> 9;
    const int s0 = m0 & 511;
    if (isT) {
        const int n0g = nb * 64;
#pragma unroll
        for (int i = 0; i < 2; i++) {
            const int item = tid + i * 512;          // 1024 float4 items
            const int mr = item >> 4, nq = item & 15;
            const float4 c  = *(const float4*)&ct[mr * 68 + nq * 4];
            const float4 bv = *(const float4*)&bh[n0g + nq * 4];
            float4 o;
            o.x = __builtin_amdgcn_exp2f((c.x + bv.x) * CC);
            o.y = __builtin_amdgcn_exp2f((c.y + bv.y) * CC);
            o.z = __builtin_amdgcn_exp2f((c.z + bv.z) * CC);
            o.w = __builtin_amdgcn_exp2f((c.w + bv.w) * CC);
            *(float4*)&Egt[(m0 + mr) * Hn + n0g + nq * 4] = o;
        }
    } else {
        const int kq0 = (nb - 4) * 16;
#pragma unroll
        for (int i = 0; i < 2; i++) {
            const int item = tid + i * 512;
            const int mr = item & 63, nq = item >> 6;
            const float4 c = *(const float4*)&ct[mr * 68 + nq * 4];
            float4 o;
            o.x = __builtin_amdgcn_exp2f(c.x * CC);
            o.y = __builtin_amdgcn_exp2f(c.y * CC);
            o.z = __builtin_amdgcn_exp2f(c.z * CC);
            o.w = __builtin_amdgcn_exp2f(c.w * CC);
            *(float4*)&Egp4[b * 131072 + (kq0 + nq) * 2048 + (s0 + mr) * 4] = o;
        }
    }
}

// ---------------------------------------------------------------------------
// attn: FROZEN R13 form (best measured 46.0-46.6us; R8-R13 occupancy/
// pipelining/packing levers all within noise or regressions). 1024 thr =
// (tp:512)x(kh:2), 4 t-rows, grid 512 -> 32 waves/CU; egt/wa2 via pipelined
// s_load; 4-way-rcp factorized tanh; fused softmax + out matvec.
// ---------------------------------------------------------------------------
__global__ __launch_bounds__(1024) void attn_kernel(
    const float* __restrict__ hsrc, const float* __restrict__ Egt,
    const float* __restrict__ Egp4, const float* __restrict__ wa2,
    const float* __restrict__ cst,
    float* __restrict__ out, float* __restrict__ out_attn)
{
    // [0,8K) attn_l[4][512] ; [8K,16K) accl[4][512] ; [16K,16.25K) red ;
    // part[8][4][64]f4 32KB aliases [8K,40K) (phase 2 only; accl/red dead)
    __shared__ char smem[40960];
    float*  attn_l = (float*)smem;
    float*  accl   = (float*)(smem + 8192);
    float*  red    = (float*)(smem + 16384);
    float4* part   = (float4*)(smem + 8192);

    const int tid = threadIdx.x;       // 0..1023
    const int tp  = tid & 511;
    const int kh  = tid >> 9;          // 0 or 1: k-half (wave-uniform)
    const int b   = blockIdx.x & 3;
    const int t0  = (blockIdx.x >> 2) << 2;

    const int kbu = __builtin_amdgcn_readfirstlane(kh << 5);

    const float* __restrict__ egt = Egt + (b * Sn + t0) * Hn;   // block-uniform
    const float4* __restrict__ ep = (const float4*)(Egp4 + b * (Hn * Sn));

    float acc[4] = {0.f, 0.f, 0.f, 0.f};

    float4 w4c  = *(const float4*)&wa2[kbu * 4];
    float4 eg0c = *(const float4*)&egt[0 * Hn + kbu * 4];
    float4 eg1c = *(const float4*)&egt[1 * Hn + kbu * 4];
    float4 eg2c = *(const float4*)&egt[2 * Hn + kbu * 4];
    float4 eg3c = *(const float4*)&egt[3 * Hn + kbu * 4];

#pragma unroll 2
    for (int kk = 0; kk < 32; kk++) {
        const int k4n = kbu + ((kk + 1) & 31);
        const float4 w4n  = *(const float4*)&wa2[k4n * 4];
        const float4 eg0n = *(const float4*)&egt[0 * Hn + k4n * 4];
        const float4 eg1n = *(const float4*)&egt[1 * Hn + k4n * 4];
        const float4 eg2n = *(const float4*)&egt[2 * Hn + k4n * 4];
        const float4 eg3n = *(const float4*)&egt[3 * Hn + k4n * 4];

        const float4 cur = ep[(kbu + kk) * Sn + tp];   // coalesced vector load

        const float4 egs[4] = {eg0c, eg1c, eg2c, eg3c};
#pragma unroll
        for (int r = 0; r < 4; r++) {
            const float4 eg = egs[r];
            const float d1 = fmaf(cur.x, eg.x, 1.0f);
            const float d2 = fmaf(cur.y, eg.y, 1.0f);
            const float d3 = fmaf(cur.z, eg.z, 1.0f);
            const float d4 = fmaf(cur.w, eg.w, 1.0f);
            const float p12 = d1 * d2, p34 = d3 * d4;
            const float n12 = fmaf(w4c.x, d2, w4c.y * d1);
            const float n34 = fmaf(w4c.z, d4, w4c.w * d3);
            const float num = fmaf(n12, p34, n34 * p12);
            acc[r] = fmaf(num, __builtin_amdgcn_rcpf(p12 * p34), acc[r]);
        }

        w4c = w4n; eg0c = eg0n; eg1c = eg1n; eg2c = eg2n; eg3c = eg3n;
    }

    if (kh == 1) {
#pragma unroll
        for (int r = 0; r < 4; r++) accl[r * 512 + tp] = acc[r];
    }
    __syncthreads();

    float ex[4];
    const float k0 = cst[0];
    if (kh == 0) {
#pragma unroll
        for (int r = 0; r < 4; r++) {
            const float a   = acc[r] + accl[r * 512 + tp];
            const float e1  = __builtin_amdgcn_exp2f(fmaf(-L2E, a, k0));
            const float sig = __builtin_amdgcn_rcpf(1.0f + e1);
            ex[r] = __builtin_amdgcn_exp2f(L2E * sig);   // sig in (0,1)
        }
        const int lane = tid & 63, wid = tid >> 6;       // wid 0..7
#pragma unroll
        for (int r = 0; r < 4; r++) {
            float v = ex[r];
#pragma unroll
            for (int off = 32; off >= 1; off >>= 1) v += __shfl_xor(v, off, 64);
            if (lane == 0) red[r * 8 + wid] = v;
        }
    }
    __syncthreads();

    if (kh == 0) {
#pragma unroll
        for (int r = 0; r < 4; r++) {
            float tot = 0.f;
#pragma unroll
            for (int i = 0; i < 8; i++) tot += red[r * 8 + i];
            const float a = ex[r] * __builtin_amdgcn_rcpf(tot);
            attn_l[r * Sn + tp] = a;
            out_attn[(b * Sn + t0 + r) * Sn + tp] = a;
        }
    }
    __syncthreads();

    // ---- phase 2: out rows = attn @ h. 16 q-groups of 32 t' each ----
    const int c4 = tid & 63;
    const int q  = tid >> 6;                 // 0..15, wave-uniform

    const float* __restrict__ hb = hsrc + (b * Sn + q * 32) * Hn + c4 * 4;

    float4 a4[4];
#pragma unroll
    for (int r = 0; r < 4; r++) a4[r] = (float4){0.f, 0.f, 0.f, 0.f};

#pragma unroll 2
    for (int j4 = 0; j4 < 8; j4++) {
        float4 wv[4];
#pragma unroll
        for (int r = 0; r < 4; r++)
            wv[r] = *(const float4*)&attn_l[r * Sn + q * 32 + j4 * 4];  // bcast
#pragma unroll
        for (int i = 0; i < 4; i++) {
            const float4 hv = *(const float4*)&hb[(j4 * 4 + i) * Hn];
#pragma unroll
            for (int r = 0; r < 4; r++) {
                const float wr = ((const float*)&wv[r])[i];
                a4[r].x = fmaf(wr, hv.x, a4[r].x);
                a4[r].y = fmaf(wr, hv.y, a4[r].y);
                a4[r].z = fmaf(wr, hv.z, a4[r].z);
                a4[r].w = fmaf(wr, hv.w, a4[r].w);
            }
        }
    }
    __syncthreads();   // accl/red reads all done; part may now alias

    if (q < 8) {
#pragma unroll
        for (int r = 0; r < 4; r++) part[(q * 4 + r) * 64 + c4] = a4[r];
    }
    __syncthreads();
    if (q >= 8) {
#pragma unroll
        for (int r = 0; r < 4; r++) {
            float4 p = part[((q - 8) * 4 + r) * 64 + c4];
            p.x += a4[r].x; p.y += a4[r].y; p.z += a4[r].z; p.w += a4[r].w;
            part[((q - 8) * 4 + r) * 64 + c4] = p;
        }
    }
    __syncthreads();

    // final: 1024 threads = 256 cols x 4 rows; sum the 8 q-partials
    {
        const int col = tid & 255;
        const int r   = tid >> 8;
        const float* pf = (const float*)part;
        float s = 0.f;
#pragma unroll
        for (int qq = 0; qq < 8; qq++)
            s += pf[((qq * 4 + r) * 64 + (col >> 2)) * 4 + (col & 3)];
        out[(b * Sn + t0 + r) * Hn + col] = s;
    }
}

extern "C" void kernel_launch(void* const* d_in, const int* in_sizes, int n_in,
                              void* d_out, int out_size, void* d_ws, size_t ws_size,
                              hipStream_t stream) {
    const float* h   = (const float*)d_in[0];
    const float* Wt  = (const float*)d_in[1];
    const float* Wtp = (const float*)d_in[2];
    const float* bh  = (const float*)d_in[3];
    const float* Wa  = (const float*)d_in[4];
    const float* ba  = (const float*)d_in[5];

    float* out      = (float*)d_out;                 // (B,S,H) = 524288
    float* out_attn = out + Bn * Sn * Hn;            // (B,S,S) = 1048576

    float* ws   = (float*)d_ws;
    float* Egt  = ws;                                 // 524288 f
    float* Egp4 = ws + 524288;                        // 524288 f
    float* wa2  = ws + 1048576;                       // 256 f
    float* cst  = ws + 1048832;                       // 1 f

    gemm_kernel<<<dim3(256), dim3(512), 0, stream>>>(
        h, Wt, Wtp, Wa, ba, bh, Egt, Egp4, wa2, cst);
    attn_kernel<<<dim3(Bn * (Sn / 4)), dim3(1024), 0, stream>>>(
        h, Egt, Egp4, wa2, cst, out, out_attn);
}